// Round 11
// baseline (114.703 us; speedup 1.0000x reference)
//
#include <hip/hip_runtime.h>
#include <hip/hip_bf16.h>
#include <stdint.h>

#define NR   4096
#define DIM  1024
#define NE   8
#define BM   128
#define BN   128
#define GBK  64

typedef __attribute__((ext_vector_type(8))) short  bf16x8;
typedef __attribute__((ext_vector_type(8))) ushort u16x8;
typedef __attribute__((ext_vector_type(4))) float  f32x4;

__device__ __forceinline__ ushort f2bf(float f) {
    union { __hip_bfloat16 h; ushort u; } cv;
    cv.h = __float2bfloat16(f);   // RNE
    return cv.u;
}

__device__ __forceinline__ void gload16(const void* g, void* l) {
    __builtin_amdgcn_global_load_lds(
        (const __attribute__((address_space(1))) unsigned int*)g,
        (__attribute__((address_space(3))) unsigned int*)l, 16, 0, 0);
}

// ---------------- K1: gate (blocks 0..255) + zero out (blocks 256..767) -----
// gate: 16 rows/block; Wg/Wn self-staged transposed into LDS (L2-hot reads);
// no atomics: writes eid[row], wpair[row], and the bf16 copy of x.
__global__ __launch_bounds__(256)
void k1_gate(const float* __restrict__ x, const float* __restrict__ noise,
             const float* __restrict__ Wg, const float* __restrict__ Wn,
             ushort* __restrict__ xbf, uint32_t* __restrict__ eid,
             float2* __restrict__ wpair, float* __restrict__ out) {
    const int tid = threadIdx.x;
    if (blockIdx.x >= 256) {                       // zero role
        const int vb = blockIdx.x - 256;           // 0..511
        float4 z = {0.f, 0.f, 0.f, 0.f};
        for (int i = vb * 256 + tid; i < NR * DIM / 4; i += 512 * 256)
            ((float4*)out)[i] = z;
        return;
    }
    __shared__ float WL[16][DIM];                  // rows 0..7 Wg^T, 8..15 Wn^T (64 KB)
#pragma unroll
    for (int j = 0; j < 4; ++j) {
        int k = j * 256 + tid;
        const float4* g4 = (const float4*)(Wg + (size_t)k * NE);
        const float4* n4 = (const float4*)(Wn + (size_t)k * NE);
        float4 g0 = g4[0], g1 = g4[1], n0 = n4[0], n1 = n4[1];
        WL[0][k] = g0.x; WL[1][k] = g0.y; WL[2][k] = g0.z; WL[3][k] = g0.w;
        WL[4][k] = g1.x; WL[5][k] = g1.y; WL[6][k] = g1.z; WL[7][k] = g1.w;
        WL[8][k]  = n0.x; WL[9][k]  = n0.y; WL[10][k] = n0.z; WL[11][k] = n0.w;
        WL[12][k] = n1.x; WL[13][k] = n1.y; WL[14][k] = n1.z; WL[15][k] = n1.w;
    }
    __syncthreads();

    const int s = tid & 15, r = tid >> 4;
    const int row = blockIdx.x * 16 + r;
    const float* xr = x + (size_t)row * DIM;
    ushort*     xbr = xbf + (size_t)row * DIM;

    float accg[NE], accn[NE];
#pragma unroll
    for (int e = 0; e < NE; ++e) { accg[e] = 0.f; accn[e] = 0.f; }

#pragma unroll
    for (int j = 0; j < 16; ++j) {
        const int k0 = j * 64 + s * 4;
        float4 xv = *(const float4*)(xr + k0);
        ushort4 xb;
        xb.x = f2bf(xv.x); xb.y = f2bf(xv.y); xb.z = f2bf(xv.z); xb.w = f2bf(xv.w);
        *(ushort4*)(xbr + k0) = xb;
#pragma unroll
        for (int e = 0; e < NE; ++e) {
            float4 wg = *(const float4*)&WL[e][k0];
            accg[e] += xv.x * wg.x + xv.y * wg.y + xv.z * wg.z + xv.w * wg.w;
        }
#pragma unroll
        for (int e = 0; e < NE; ++e) {
            float4 wn = *(const float4*)&WL[8 + e][k0];
            accn[e] += xv.x * wn.x + xv.y * wn.y + xv.z * wn.z + xv.w * wn.w;
        }
    }
#pragma unroll
    for (int e = 0; e < NE; ++e) {
#pragma unroll
        for (int off = 8; off; off >>= 1) {
            accg[e] += __shfl_down(accg[e], off, 16);
            accn[e] += __shfl_down(accn[e], off, 16);
        }
    }
    if (s == 0) {
        float H[NE];
#pragma unroll
        for (int e = 0; e < NE; ++e) {
            float z  = accn[e];
            float sp = (z > 0.f) ? (z + log1pf(expf(-z))) : log1pf(expf(z));
            H[e] = accg[e] + noise[e] * sp;
        }
        int e0 = 0; float v0 = H[0];
#pragma unroll
        for (int k = 1; k < 8; ++k) if (H[k] > v0) { v0 = H[k]; e0 = k; }
        int e1 = -1; float v1 = 0.f;
#pragma unroll
        for (int k = 0; k < 8; ++k)
            if (k != e0 && (e1 < 0 || H[k] > v1)) { v1 = H[k]; e1 = k; }
        float rr = expf(v1 - v0);
        float w0 = 1.f / (1.f + rr), w1 = 1.f - w0;
        eid[row] = (uint32_t)e0 | ((uint32_t)e1 << 8);
        float2 wp; wp.x = w0; wp.y = w1;
        wpair[row] = wp;
    }
}

// ---------------- K2: We conversion (blocks 0..2047) | bucket build (2048..2055)
__global__ __launch_bounds__(256)
void k2_conv(const float* __restrict__ We, ushort* __restrict__ WeT,
             const uint32_t* __restrict__ eid, const float2* __restrict__ wpair,
             int* __restrict__ cnt, int* __restrict__ idxl, float* __restrict__ wl) {
    const int tid = threadIdx.x;
    if (blockIdx.x < 2048) {
        // ---- conv role: We [e][k][c] f32 -> WeT [e][c][k] bf16 ----
        __shared__ float smem[64 * 68];
        const int b  = blockIdx.x;                 // e*256 + kt*16 + ct
        const int e  = b >> 8, kt = (b >> 4) & 15, ct = b & 15;
        const float* src = We + ((size_t)e * DIM + (size_t)kt * 64) * DIM + ct * 64;
#pragma unroll
        for (int j = 0; j < 4; ++j) {
            int idx = tid + j * 256;
            int rr = idx >> 4, c4 = idx & 15;
            *(float4*)&smem[rr * 68 + c4 * 4] = *(const float4*)(src + (size_t)rr * DIM + c4 * 4);
        }
        __syncthreads();
        ushort* dst = WeT + ((size_t)e * DIM + (size_t)ct * 64) * DIM + kt * 64;
#pragma unroll
        for (int j = 0; j < 2; ++j) {
            int u = tid + j * 256;
            int c = u >> 3, ch = u & 7;
            ushort tmp[8];
#pragma unroll
            for (int q = 0; q < 8; ++q) tmp[q] = f2bf(smem[(ch * 8 + q) * 68 + c]);
            *(u16x8*)(dst + (size_t)c * DIM + ch * 8) = *(u16x8*)tmp;
        }
    } else {
        // ---- bucket role: merged per-expert compaction (deterministic) ----
        const int ex = blockIdx.x - 2048;          // 0..7
        __shared__ int base;
        __shared__ int wsum[4];
        if (tid == 0) base = 0;
        const int wid = tid >> 6, lane = tid & 63;
        int* bidx = idxl + (size_t)ex * NR;
        float* bwl = wl + (size_t)ex * NR;

        for (int c0 = 0; c0 < NR; c0 += 256) {
            const int row = c0 + tid;
            const uint32_t em = eid[row];
            const bool m0 = (int)(em & 255u) == ex;
            const bool m1 = (int)((em >> 8) & 255u) == ex;
            const bool m = m0 || m1;
            const unsigned long long bal = __ballot(m);
            if (lane == 0) wsum[wid] = __popcll(bal);
            __syncthreads();
            int wbase = base;
            for (int i = 0; i < wid; ++i) wbase += wsum[i];
            const int pos = wbase + __popcll(bal & ((1ull << lane) - 1ull));
            if (m) {
                bidx[pos] = row;
                float2 wp = wpair[row];
                bwl[pos]  = m0 ? wp.x : wp.y;
            }
            __syncthreads();
            if (tid == 0) base += wsum[0] + wsum[1] + wsum[2] + wsum[3];
            __syncthreads();
        }
        if (tid == 0) cnt[ex] = base;
    }
}

// ---------------- grouped expert GEMM: R5 loop, merged buckets, atomics -----
// 128x128, BK=64, dbuf-2, vmcnt(8) counted prefetch, 2 blocks/CU.
__global__ __launch_bounds__(256, 2)
void moe_gemm(const ushort* __restrict__ xbf, const ushort* __restrict__ WeT,
              const float* __restrict__ be, const int* __restrict__ cnt,
              const int* __restrict__ idxl, const float* __restrict__ wl,
              float* __restrict__ out) {
    __shared__ ushort Al[2][BM][GBK];     // 32 KB
    __shared__ ushort Bl[2][BM][GBK];     // 32 KB

    const int q8 = gridDim.x >> 3;
    const int W  = (blockIdx.x & 7) * q8 + (blockIdx.x >> 3);
    const int item = W >> 3, cT = W & 7;

    // worklist: item -> (bucket, row-tile) via prefix of ceil(cnt/BM), 8 buckets
    int bucket = -1, tile = 0, accp = 0;
#pragma unroll
    for (int b = 0; b < NE; ++b) {
        int t = (cnt[b] + BM - 1) >> 7;
        if (bucket < 0 && item < accp + t) { bucket = b; tile = item - accp; }
        accp += t;
    }
    if (bucket < 0) return;
    const int count  = cnt[bucket];
    const int nrowsv = min(BM, count - tile * BM);
    const int e  = bucket;
    const int c0 = cT * BN;
    const int*   rows = idxl + (size_t)bucket * NR + tile * BM;
    const float* wrow = wl   + (size_t)bucket * NR + tile * BM;

    const int tid = threadIdx.x, wid = tid >> 6, lane = tid & 63;
    const int wr = (wid >> 1) * 64, wc = (wid & 1) * 64;
    const int l16 = lane & 15, lhi = lane >> 4;
    const int lr8 = lane >> 3, lc8 = lane & 7;
    const int chunkp = lc8 ^ lr8;

    const ushort* aptr[4];
    const ushort* bptr[4];
#pragma unroll
    for (int q = 0; q < 4; ++q) {
        int r  = wid * 32 + q * 8 + lr8;
        int gr = rows[min(r, nrowsv - 1)];
        aptr[q] = xbf + (size_t)gr * DIM + chunkp * 8;
        int c = c0 + wid * 32 + q * 8 + lr8;
        bptr[q] = WeT + ((size_t)(e * DIM + c)) * DIM + chunkp * 8;
    }

    f32x4 acc[4][4];
#pragma unroll
    for (int m = 0; m < 4; ++m)
#pragma unroll
        for (int n = 0; n < 4; ++n) { f32x4 z = {0.f, 0.f, 0.f, 0.f}; acc[m][n] = z; }

#pragma unroll
    for (int q = 0; q < 4; ++q) {
        gload16(aptr[q], &Al[0][wid * 32 + q * 8][0]);
        gload16(bptr[q], &Bl[0][wid * 32 + q * 8][0]);
    }

    for (int s = 0; s < DIM / GBK; ++s) {
        const int buf = s & 1;
        if (s + 1 < DIM / GBK) {
            const int nb = buf ^ 1, k0 = (s + 1) * GBK;
#pragma unroll
            for (int q = 0; q < 4; ++q) {
                gload16(aptr[q] + k0, &Al[nb][wid * 32 + q * 8][0]);
                gload16(bptr[q] + k0, &Bl[nb][wid * 32 + q * 8][0]);
            }
            asm volatile("s_waitcnt vmcnt(8)" ::: "memory");
        } else {
            asm volatile("s_waitcnt vmcnt(0)" ::: "memory");
        }
        __builtin_amdgcn_s_barrier();

        const ushort* Ab = &Al[buf][0][0];
        const ushort* Bb = &Bl[buf][0][0];
#pragma unroll
        for (int h = 0; h < 2; ++h) {
            bf16x8 af[4], bfr[4];
            const int chb = (h * 4 + lhi) ^ (l16 & 7);
#pragma unroll
            for (int m = 0; m < 4; ++m) {
                int rr = wr + m * 16 + l16;
                af[m] = *(const bf16x8*)(Ab + rr * GBK + chb * 8);
            }
#pragma unroll
            for (int n = 0; n < 4; ++n) {
                int rr = wc + n * 16 + l16;
                bfr[n] = *(const bf16x8*)(Bb + rr * GBK + chb * 8);
            }
#pragma unroll
            for (int m = 0; m < 4; ++m)
#pragma unroll
                for (int n = 0; n < 4; ++n)
                    acc[m][n] = __builtin_amdgcn_mfma_f32_16x16x32_bf16(af[m], bfr[n], acc[m][n], 0, 0, 0);
        }
        asm volatile("s_waitcnt lgkmcnt(0)" ::: "memory");
        __builtin_amdgcn_s_barrier();
    }

    // epilogue: out += w * (acc + be); exactly 2 commutative adds per element
    float bev[4];
#pragma unroll
    for (int n = 0; n < 4; ++n) bev[n] = be[(size_t)e * DIM + c0 + wc + n * 16 + l16];
#pragma unroll
    for (int m = 0; m < 4; ++m) {
#pragma unroll
        for (int r = 0; r < 4; ++r) {
            int rl = wr + m * 16 + lhi * 4 + r;
            if (rl < nrowsv) {
                int   gr = rows[rl];
                float w  = wrow[rl];
                float* op = out + (size_t)gr * DIM + c0 + wc;
#pragma unroll
                for (int n = 0; n < 4; ++n)
                    atomicAdd(&op[n * 16 + l16], w * (acc[m][n][r] + bev[n]));
            }
        }
    }
}

extern "C" void kernel_launch(void* const* d_in, const int* in_sizes, int n_in,
                              void* d_out, int out_size, void* d_ws, size_t ws_size,
                              hipStream_t stream) {
    const float* x     = (const float*)d_in[0];
    const float* noise = (const float*)d_in[1];
    const float* Wg    = (const float*)d_in[2];
    const float* Wn    = (const float*)d_in[3];
    const float* We    = (const float*)d_in[4];
    const float* be    = (const float*)d_in[5];
    float* out = (float*)d_out;

    char* w = (char*)d_ws;
    size_t off = 256;
    int*      cnt   = (int*)w;
    int*      idxl  = (int*)(w + off);      off += (size_t)NE * NR * 4;       // 128 KB
    float*    wl    = (float*)(w + off);    off += (size_t)NE * NR * 4;       // 128 KB
    uint32_t* eid   = (uint32_t*)(w + off); off += (size_t)NR * 4;            // 16 KB
    float2*   wpair = (float2*)(w + off);   off += (size_t)NR * 8;            // 32 KB
    off = (off + 255) & ~(size_t)255;
    ushort* xbf = (ushort*)(w + off); off += (size_t)NR * DIM * 2;            // 8 MB
    ushort* WeT = (ushort*)(w + off); off += (size_t)NE * DIM * DIM * 2;      // 16 MB

    k1_gate<<<768, 256, 0, stream>>>(x, noise, Wg, Wn, xbf, eid, wpair, out);
    k2_conv<<<2056, 256, 0, stream>>>(We, WeT, eid, wpair, cnt, idxl, wl);
    moe_gemm<<<72 * 8, 256, 0, stream>>>(xbf, WeT, be, cnt, idxl, wl, out);
}

// Round 12
// 97.711 us; speedup vs baseline: 1.1739x; 1.1739x over previous
//
#include <hip/hip_runtime.h>
#include <hip/hip_bf16.h>
#include <stdint.h>

#define NR   4096
#define DIM  1024
#define NE   8
#define BM   256
#define BN   128
#define GBK  64
#define LDSA (BM * GBK)           // 16384 ushorts
#define LDSB (BN * GBK)           // 8192 ushorts
#define LSLOT (LDSA + LDSB)       // 24576 ushorts = 48 KB per buffer

typedef __attribute__((ext_vector_type(8))) short  bf16x8;
typedef __attribute__((ext_vector_type(8))) ushort u16x8;
typedef __attribute__((ext_vector_type(4))) float  f32x4;

__device__ __forceinline__ ushort f2bf(float f) {
    union { __hip_bfloat16 h; ushort u; } cv;
    cv.h = __float2bfloat16(f);   // RNE
    return cv.u;
}

__device__ __forceinline__ void gload16(const void* g, void* l) {
    __builtin_amdgcn_global_load_lds(
        (const __attribute__((address_space(1))) unsigned int*)g,
        (__attribute__((address_space(3))) unsigned int*)l, 16, 0, 0);
}

// ---------------- K1: WT transpose (blocks 0..7) + zero out (blocks 8..519) --
__global__ __launch_bounds__(256)
void k1_prep(const float* __restrict__ Wg, const float* __restrict__ Wn,
             float* __restrict__ WT, float* __restrict__ out) {
    const int tid = threadIdx.x;
    if (blockIdx.x < 8) {
        const int k    = blockIdx.x * 128 + (tid >> 1);
        const int half = tid & 1;
        const float* src = half ? Wn : Wg;
        const float4* s4 = (const float4*)(src + (size_t)k * NE);
        float4 a = s4[0], b = s4[1];
        float* d = WT + (size_t)half * 8 * DIM;
        d[(size_t)0 * DIM + k] = a.x; d[(size_t)1 * DIM + k] = a.y;
        d[(size_t)2 * DIM + k] = a.z; d[(size_t)3 * DIM + k] = a.w;
        d[(size_t)4 * DIM + k] = b.x; d[(size_t)5 * DIM + k] = b.y;
        d[(size_t)6 * DIM + k] = b.z; d[(size_t)7 * DIM + k] = b.w;
    } else {
        const int vb = blockIdx.x - 8;
        float4 z = {0.f, 0.f, 0.f, 0.f};
        for (int i = vb * 256 + tid; i < NR * DIM / 4; i += 512 * 256)
            ((float4*)out)[i] = z;
    }
}

// ---------------- K2: We convert+transpose (blocks 0..2047) | gate (2048..3071)
__global__ __launch_bounds__(256)
void k2_main(const float* __restrict__ We, ushort* __restrict__ WeT,
             const float* __restrict__ x, const float* __restrict__ noise,
             const float* __restrict__ WT, ushort* __restrict__ xbf,
             uint32_t* __restrict__ eid, float2* __restrict__ wpair) {
    __shared__ float smem[64 * 68];
    const int tid = threadIdx.x;
    if (blockIdx.x < 2048) {
        const int b  = blockIdx.x;
        const int e  = b >> 8, kt = (b >> 4) & 15, ct = b & 15;
        const float* src = We + ((size_t)e * DIM + (size_t)kt * 64) * DIM + ct * 64;
#pragma unroll
        for (int j = 0; j < 4; ++j) {
            int idx = tid + j * 256;
            int r = idx >> 4, c4 = idx & 15;
            *(float4*)&smem[r * 68 + c4 * 4] = *(const float4*)(src + (size_t)r * DIM + c4 * 4);
        }
        __syncthreads();
        ushort* dst = WeT + ((size_t)e * DIM + (size_t)ct * 64) * DIM + kt * 64;
#pragma unroll
        for (int j = 0; j < 2; ++j) {
            int u = tid + j * 256;
            int c = u >> 3, ch = u & 7;
            ushort tmp[8];
#pragma unroll
            for (int q = 0; q < 8; ++q) tmp[q] = f2bf(smem[(ch * 8 + q) * 68 + c]);
            *(u16x8*)(dst + (size_t)c * DIM + ch * 8) = *(u16x8*)tmp;
        }
    } else {
        const int w = tid >> 6, l = tid & 63;
        const int row = (blockIdx.x - 2048) * 4 + w;
        const float* xr = x + (size_t)row * DIM;

        float4 xv[4];
#pragma unroll
        for (int q = 0; q < 4; ++q) xv[q] = *(const float4*)(xr + q * 256 + l * 4);
#pragma unroll
        for (int q = 0; q < 4; ++q) {
            ushort4 xb;
            xb.x = f2bf(xv[q].x); xb.y = f2bf(xv[q].y);
            xb.z = f2bf(xv[q].z); xb.w = f2bf(xv[q].w);
            *(ushort4*)(xbf + (size_t)row * DIM + q * 256 + l * 4) = xb;
        }

        float acc[16];
#pragma unroll
        for (int u = 0; u < 16; ++u) {
            const float* wr_ = WT + (size_t)u * DIM + l * 4;
            float s = 0.f;
#pragma unroll
            for (int q = 0; q < 4; ++q) {
                float4 wv = *(const float4*)(wr_ + q * 256);
                s += xv[q].x * wv.x + xv[q].y * wv.y + xv[q].z * wv.z + xv[q].w * wv.w;
            }
            acc[u] = s;
        }
#pragma unroll
        for (int u = 0; u < 16; ++u) smem[(w * 64 + l) * 17 + u] = acc[u];
        asm volatile("s_waitcnt lgkmcnt(0)" ::: "memory");
        const int c = l >> 4, u = l & 15;
        float v = 0.f;
#pragma unroll
        for (int i = 0; i < 16; ++i) v += smem[(w * 64 + c * 16 + i) * 17 + u];
        v += __shfl_xor(v, 16, 64);
        v += __shfl_xor(v, 32, 64);

        const int e = l & 7;
        float ag = __shfl(v, e, 64);
        float an = __shfl(v, e + 8, 64);
        float sp = (an > 0.f) ? (an + log1pf(expf(-an))) : log1pf(expf(an));
        float H  = ag + noise[e] * sp;

        float Hh[8];
#pragma unroll
        for (int k = 0; k < 8; ++k) Hh[k] = __shfl(H, k, 64);
        if (l == 0) {
            int e0 = 0; float v0 = Hh[0];
#pragma unroll
            for (int k = 1; k < 8; ++k) if (Hh[k] > v0) { v0 = Hh[k]; e0 = k; }
            int e1 = -1; float v1 = 0.f;
#pragma unroll
            for (int k = 0; k < 8; ++k)
                if (k != e0 && (e1 < 0 || Hh[k] > v1)) { v1 = Hh[k]; e1 = k; }
            float rr = expf(v1 - v0);
            float w0 = 1.f / (1.f + rr), w1 = 1.f - w0;
            eid[row] = (uint32_t)e0 | ((uint32_t)e1 << 8);
            float2 wp; wp.x = w0; wp.y = w1;
            wpair[row] = wp;
        }
    }
}

// ---------------- bucket build: merged per-expert buckets (8) ---------------
__global__ __launch_bounds__(1024)
void bucket_build(const uint32_t* __restrict__ eid, const float2* __restrict__ wpair,
                  int* __restrict__ cnt, int* __restrict__ idxl, float* __restrict__ wl) {
    const int ex = blockIdx.x;              // 0..7
    __shared__ int base;
    __shared__ int wsum[16];
    if (threadIdx.x == 0) base = 0;
    const int wid = threadIdx.x >> 6, lane = threadIdx.x & 63;
    int* bidx = idxl + (size_t)ex * NR;
    float* bwl = wl + (size_t)ex * NR;

    for (int c0 = 0; c0 < NR; c0 += 1024) {
        const int row = c0 + threadIdx.x;
        const uint32_t em = eid[row];
        const bool m0 = (int)(em & 255u) == ex;
        const bool m1 = (int)((em >> 8) & 255u) == ex;
        const bool m = m0 || m1;
        const unsigned long long bal = __ballot(m);
        if (lane == 0) wsum[wid] = __popcll(bal);
        __syncthreads();
        int wbase = base;
        for (int i = 0; i < wid; ++i) wbase += wsum[i];
        const int pos = wbase + __popcll(bal & ((1ull << lane) - 1ull));
        if (m) {
            bidx[pos] = row;
            float2 wp = wpair[row];
            bwl[pos]  = m0 ? wp.x : wp.y;
        }
        __syncthreads();
        if (threadIdx.x == 0) {
            int s = 0;
#pragma unroll
            for (int i = 0; i < 16; ++i) s += wsum[i];
            base += s;
        }
        __syncthreads();
    }
    if (threadIdx.x == 0) cnt[ex] = base;
}

// ---------------- grouped expert GEMM: 256x128, 8 waves, dbuf-2, 1 block/CU --
// R5's verified K-loop body/swizzles at 8-wave scale: 32 MFMA per wave per
// K-step between one barrier pair; counted vmcnt(6) prefetch.
__global__ __launch_bounds__(512, 1)
void moe_gemm(const ushort* __restrict__ xbf, const ushort* __restrict__ WeT,
              const float* __restrict__ be, const int* __restrict__ cnt,
              const int* __restrict__ idxl, const float* __restrict__ wl,
              float* __restrict__ out) {
    extern __shared__ ushort lds[];          // 2 * LSLOT = 96 KB

    const int q8 = gridDim.x >> 3;
    const int W  = (blockIdx.x & 7) * q8 + (blockIdx.x >> 3);
    const int item = W >> 3, cT = W & 7;

    // worklist: item -> (bucket, row-tile) via prefix of ceil(cnt/BM)
    int bucket = -1, tile = 0, accp = 0;
#pragma unroll
    for (int b = 0; b < NE; ++b) {
        int t = (cnt[b] + BM - 1) >> 8;
        if (bucket < 0 && item < accp + t) { bucket = b; tile = item - accp; }
        accp += t;
    }
    if (bucket < 0) return;
    const int count  = cnt[bucket];
    const int nrows  = min(BM, count - tile * BM);
    const int e  = bucket;
    const int c0 = cT * BN;
    const int*   rows = idxl + (size_t)bucket * NR + tile * BM;
    const float* wrow = wl   + (size_t)bucket * NR + tile * BM;

    const int tid = threadIdx.x, wid = tid >> 6, lane = tid & 63;
    const int wr = (wid >> 1) * 64, wc = (wid & 1) * 64;   // 4M x 2N wave grid
    const int l16 = lane & 15, lhi = lane >> 4;
    const int lr8 = lane >> 3, lc8 = lane & 7;
    const int chunkp = lc8 ^ lr8;                          // R5 stage swizzle

    // A: wave w stages rows w*32 + q*8 + lr8 (q=0..3); B: rows w*16 + q*8 + lr8 (q=0..1)
    const ushort* aptr[4];
    const ushort* bptr[2];
#pragma unroll
    for (int q = 0; q < 4; ++q) {
        int r  = wid * 32 + q * 8 + lr8;
        int gr = rows[min(r, nrows - 1)];
        aptr[q] = xbf + (size_t)gr * DIM + chunkp * 8;
    }
#pragma unroll
    for (int q = 0; q < 2; ++q) {
        int c = c0 + wid * 16 + q * 8 + lr8;
        bptr[q] = WeT + ((size_t)(e * DIM + c)) * DIM + chunkp * 8;
    }

    f32x4 acc[4][4];
#pragma unroll
    for (int m = 0; m < 4; ++m)
#pragma unroll
        for (int n = 0; n < 4; ++n) { f32x4 z = {0.f, 0.f, 0.f, 0.f}; acc[m][n] = z; }

#define STAGE(T, BUF) do {                                                     \
    const int _k0 = (T) * GBK;                                                 \
    ushort* _a = lds + (BUF) * LSLOT;                                          \
    ushort* _bb = _a + LDSA;                                                   \
    _Pragma("unroll")                                                          \
    for (int q = 0; q < 4; ++q)                                                \
        gload16(aptr[q] + _k0, _a + (wid * 32 + q * 8) * GBK);                 \
    _Pragma("unroll")                                                          \
    for (int q = 0; q < 2; ++q)                                                \
        gload16(bptr[q] + _k0, _bb + (wid * 16 + q * 8) * GBK);                \
} while (0)

    const int NS = DIM / GBK;                              // 16
    STAGE(0, 0);
    for (int s = 0; s < NS; ++s) {
        const int buf = s & 1;
        if (s + 1 < NS) {
            STAGE(s + 1, buf ^ 1);
            asm volatile("s_waitcnt vmcnt(6)" ::: "memory");   // tile s landed
        } else {
            asm volatile("s_waitcnt vmcnt(0)" ::: "memory");
        }
        __builtin_amdgcn_s_barrier();

        const ushort* Ab = lds + buf * LSLOT;
        const ushort* Bb = Ab + LDSA;
#pragma unroll
        for (int h = 0; h < 2; ++h) {
            bf16x8 af[4], bfr[4];
            const int chb = (h * 4 + lhi) ^ (l16 & 7);     // R5 read swizzle
#pragma unroll
            for (int m = 0; m < 4; ++m)
                af[m] = *(const bf16x8*)(Ab + (wr + m * 16 + l16) * GBK + chb * 8);
#pragma unroll
            for (int n = 0; n < 4; ++n)
                bfr[n] = *(const bf16x8*)(Bb + (wc + n * 16 + l16) * GBK + chb * 8);
#pragma unroll
            for (int m = 0; m < 4; ++m)
#pragma unroll
                for (int n = 0; n < 4; ++n)
                    acc[m][n] = __builtin_amdgcn_mfma_f32_16x16x32_bf16(af[m], bfr[n], acc[m][n], 0, 0, 0);
        }
        asm volatile("s_waitcnt lgkmcnt(0)" ::: "memory");
        __builtin_amdgcn_s_barrier();
    }
#undef STAGE

    // epilogue: out += w * (acc + be); exactly 2 commutative adds per element
    float bev[4];
#pragma unroll
    for (int n = 0; n < 4; ++n) bev[n] = be[(size_t)e * DIM + c0 + wc + n * 16 + l16];
#pragma unroll
    for (int m = 0; m < 4; ++m) {
#pragma unroll
        for (int r = 0; r < 4; ++r) {
            int rl = wr + m * 16 + lhi * 4 + r;
            if (rl < nrows) {
                int   gr = rows[rl];
                float w  = wrow[rl];
                float* op = out + (size_t)gr * DIM + c0 + wc;
#pragma unroll
                for (int n = 0; n < 4; ++n)
                    atomicAdd(&op[n * 16 + l16], w * (acc[m][n][r] + bev[n]));
            }
        }
    }
}

extern "C" void kernel_launch(void* const* d_in, const int* in_sizes, int n_in,
                              void* d_out, int out_size, void* d_ws, size_t ws_size,
                              hipStream_t stream) {
    const float* x     = (const float*)d_in[0];
    const float* noise = (const float*)d_in[1];
    const float* Wg    = (const float*)d_in[2];
    const float* Wn    = (const float*)d_in[3];
    const float* We    = (const float*)d_in[4];
    const float* be    = (const float*)d_in[5];
    float* out = (float*)d_out;

    char* w = (char*)d_ws;
    size_t off = 256;
    int*      cnt   = (int*)w;
    int*      idxl  = (int*)(w + off);      off += (size_t)NE * NR * 4;       // 128 KB
    float*    wl    = (float*)(w + off);    off += (size_t)NE * NR * 4;       // 128 KB
    uint32_t* eid   = (uint32_t*)(w + off); off += (size_t)NR * 4;            // 16 KB
    float2*   wpair = (float2*)(w + off);   off += (size_t)NR * 8;            // 32 KB
    off = (off + 255) & ~(size_t)255;
    float*  WT  = (float*)(w + off);  off += (size_t)16 * DIM * 4;            // 64 KB
    ushort* xbf = (ushort*)(w + off); off += (size_t)NR * DIM * 2;            // 8 MB
    ushort* WeT = (ushort*)(w + off); off += (size_t)NE * DIM * DIM * 2;      // 16 MB

    (void)hipFuncSetAttribute((const void*)moe_gemm,
                              hipFuncAttributeMaxDynamicSharedMemorySize,
                              2 * LSLOT * (int)sizeof(ushort));

    k1_prep<<<520, 256, 0, stream>>>(Wg, Wn, WT, out);
    k2_main<<<3072, 256, 0, stream>>>(We, WeT, x, noise, WT, xbf, eid, wpair);
    bucket_build<<<NE, 1024, 0, stream>>>(eid, wpair, cnt, idxl, wl);
    moe_gemm<<<40 * 8, 512, 2 * LSLOT * sizeof(ushort), stream>>>(xbf, WeT, be, cnt, idxl, wl, out);
}

// Round 13
// 88.305 us; speedup vs baseline: 1.2989x; 1.1065x over previous
//
#include <hip/hip_runtime.h>
#include <hip/hip_bf16.h>
#include <stdint.h>

#define NR   4096
#define DIM  1024
#define NE   8
#define BM   128
#define BN   128
#define GBK  64

typedef __attribute__((ext_vector_type(8))) short  bf16x8;
typedef __attribute__((ext_vector_type(8))) ushort u16x8;
typedef __attribute__((ext_vector_type(4))) float  f32x4;

__device__ __forceinline__ ushort f2bf(float f) {
    union { __hip_bfloat16 h; ushort u; } cv;
    cv.h = __float2bfloat16(f);   // RNE
    return cv.u;
}

__device__ __forceinline__ void gload16(const void* g, void* l) {
    __builtin_amdgcn_global_load_lds(
        (const __attribute__((address_space(1))) unsigned int*)g,
        (__attribute__((address_space(3))) unsigned int*)l, 16, 0, 0);
}

// ---------------- K1: We convert+transpose (blocks 0..2047) | gate (2048..3071)
// gate reads Wg/Wn RAW (no WT dependency): lane l owns k = j*64 + l.
__global__ __launch_bounds__(256)
void k1_main(const float* __restrict__ We, ushort* __restrict__ WeT,
             const float* __restrict__ x, const float* __restrict__ noise,
             const float* __restrict__ Wg, const float* __restrict__ Wn,
             ushort* __restrict__ xbf,
             uint32_t* __restrict__ eid, float2* __restrict__ wpair) {
    __shared__ float smem[64 * 68];                   // both roles
    const int tid = threadIdx.x;
    if (blockIdx.x < 2048) {
        // ---- conv role: We [e][k][c] f32 -> WeT [e][c][k] bf16 (validated) ----
        const int b  = blockIdx.x;                    // e*256 + kt*16 + ct
        const int e  = b >> 8, kt = (b >> 4) & 15, ct = b & 15;
        const float* src = We + ((size_t)e * DIM + (size_t)kt * 64) * DIM + ct * 64;
#pragma unroll
        for (int j = 0; j < 4; ++j) {
            int idx = tid + j * 256;
            int r = idx >> 4, c4 = idx & 15;
            *(float4*)&smem[r * 68 + c4 * 4] = *(const float4*)(src + (size_t)r * DIM + c4 * 4);
        }
        __syncthreads();
        ushort* dst = WeT + ((size_t)e * DIM + (size_t)ct * 64) * DIM + kt * 64;
#pragma unroll
        for (int j = 0; j < 2; ++j) {
            int u = tid + j * 256;
            int c = u >> 3, ch = u & 7;
            ushort tmp[8];
#pragma unroll
            for (int q = 0; q < 8; ++q) tmp[q] = f2bf(smem[(ch * 8 + q) * 68 + c]);
            *(u16x8*)(dst + (size_t)c * DIM + ch * 8) = *(u16x8*)tmp;
        }
    } else {
        // ---- gate role: one wave per row; raw W rows; no atomics ----
        const int w = tid >> 6, l = tid & 63;
        const int row = (blockIdx.x - 2048) * 4 + w;
        const float* xr = x + (size_t)row * DIM;
        ushort*     xbr = xbf + (size_t)row * DIM;

        float ag[8], an[8];
#pragma unroll
        for (int e = 0; e < 8; ++e) { ag[e] = 0.f; an[e] = 0.f; }

#pragma unroll
        for (int j = 0; j < 16; ++j) {
            const int k = j * 64 + l;
            float xv = xr[k];
            xbr[k] = f2bf(xv);
            const float4* g4 = (const float4*)(Wg + (size_t)k * NE);
            const float4* n4 = (const float4*)(Wn + (size_t)k * NE);
            float4 g0 = g4[0], g1 = g4[1], n0 = n4[0], n1 = n4[1];
            ag[0] += xv * g0.x; ag[1] += xv * g0.y; ag[2] += xv * g0.z; ag[3] += xv * g0.w;
            ag[4] += xv * g1.x; ag[5] += xv * g1.y; ag[6] += xv * g1.z; ag[7] += xv * g1.w;
            an[0] += xv * n0.x; an[1] += xv * n0.y; an[2] += xv * n0.z; an[3] += xv * n0.w;
            an[4] += xv * n1.x; an[5] += xv * n1.y; an[6] += xv * n1.z; an[7] += xv * n1.w;
        }
        // LDS transpose-reduce (R5-verified): red(w,l,u) = smem[(w*64+l)*17 + u]
#pragma unroll
        for (int u = 0; u < 16; ++u)
            smem[(w * 64 + l) * 17 + u] = (u < 8) ? ag[u] : an[u - 8];
        asm volatile("s_waitcnt lgkmcnt(0)" ::: "memory");
        const int c = l >> 4, u = l & 15;
        float v = 0.f;
#pragma unroll
        for (int i = 0; i < 16; ++i) v += smem[(w * 64 + c * 16 + i) * 17 + u];
        v += __shfl_xor(v, 16, 64);
        v += __shfl_xor(v, 32, 64);

        const int e = l & 7;
        float agv = __shfl(v, e, 64);
        float anv = __shfl(v, e + 8, 64);
        float sp  = (anv > 0.f) ? (anv + log1pf(expf(-anv))) : log1pf(expf(anv));
        float H   = agv + noise[e] * sp;

        float Hh[8];
#pragma unroll
        for (int k = 0; k < 8; ++k) Hh[k] = __shfl(H, k, 64);
        if (l == 0) {
            int e0 = 0; float v0 = Hh[0];
#pragma unroll
            for (int k = 1; k < 8; ++k) if (Hh[k] > v0) { v0 = Hh[k]; e0 = k; }
            int e1 = -1; float v1 = 0.f;
#pragma unroll
            for (int k = 0; k < 8; ++k)
                if (k != e0 && (e1 < 0 || Hh[k] > v1)) { v1 = Hh[k]; e1 = k; }
            float rr = expf(v1 - v0);
            float w0 = 1.f / (1.f + rr), w1 = 1.f - w0;
            eid[row] = (uint32_t)e0 | ((uint32_t)e1 << 8);
            float2 wp; wp.x = w0; wp.y = w1;
            wpair[row] = wp;
        }
    }
}

// ---------------- bucket build: 16 slot-separated buckets (R5-verified) ------
__global__ __launch_bounds__(1024)
void bucket_build(const uint32_t* __restrict__ eid, const float2* __restrict__ wpair,
                  int* __restrict__ cnt, int* __restrict__ idxl, float* __restrict__ wl) {
    const int bucket = blockIdx.x;          // 0..15
    const int slot = bucket >> 3, ex = bucket & 7;
    __shared__ int base;
    __shared__ int wsum[16];
    if (threadIdx.x == 0) base = 0;
    const int wid = threadIdx.x >> 6, lane = threadIdx.x & 63;
    int* bidx = idxl + (size_t)bucket * NR;
    float* bwl = wl + (size_t)bucket * NR;

    for (int c0 = 0; c0 < NR; c0 += 1024) {
        const int row = c0 + threadIdx.x;
        const uint32_t em = eid[row];
        const int e = slot ? (int)((em >> 8) & 255u) : (int)(em & 255u);
        const bool m = (e == ex);
        const unsigned long long bal = __ballot(m);
        if (lane == 0) wsum[wid] = __popcll(bal);
        __syncthreads();
        int wbase = base;
        for (int i = 0; i < wid; ++i) wbase += wsum[i];
        const int pos = wbase + __popcll(bal & ((1ull << lane) - 1ull));
        if (m) {
            bidx[pos] = row;
            float2 wp = wpair[row];
            bwl[pos]  = slot ? wp.y : wp.x;
        }
        __syncthreads();
        if (threadIdx.x == 0) {
            int s = 0;
#pragma unroll
            for (int i = 0; i < 16; ++i) s += wsum[i];
            base += s;
        }
        __syncthreads();
    }
    if (threadIdx.x == 0) cnt[bucket] = base;
}

// ---------------- grouped expert GEMM: R5 K-loop verbatim, two-pass RMW ------
// PASS 0: slot-0 buckets, plain store. PASS 1: slot-1, non-atomic out += v
// (safe: dispatches serialize; one writer per element per dispatch).
template<int PASS>
__global__ __launch_bounds__(256, 2)
void moe_gemm(const ushort* __restrict__ xbf, const ushort* __restrict__ WeT,
              const float* __restrict__ be, const int* __restrict__ cnt,
              const int* __restrict__ idxl, const float* __restrict__ wl,
              float* __restrict__ out) {
    __shared__ ushort Al[2][BM][GBK];     // 32 KB
    __shared__ ushort Bl[2][BM][GBK];     // 32 KB

    const int q8 = gridDim.x >> 3;
    const int W  = (blockIdx.x & 7) * q8 + (blockIdx.x >> 3);
    const int item = W >> 3, cT = W & 7;

    // worklist over this pass's 8 buckets
    int bucket = -1, tile = 0, accp = 0;
#pragma unroll
    for (int b = 0; b < NE; ++b) {
        int t = (cnt[PASS * NE + b] + BM - 1) >> 7;
        if (bucket < 0 && item < accp + t) { bucket = PASS * NE + b; tile = item - accp; }
        accp += t;
    }
    if (bucket < 0) return;
    const int count  = cnt[bucket];
    const int nrowsv = min(BM, count - tile * BM);
    const int e  = bucket & 7;
    const int c0 = cT * BN;
    const int*   rows = idxl + (size_t)bucket * NR + tile * BM;
    const float* wrow = wl   + (size_t)bucket * NR + tile * BM;

    const int tid = threadIdx.x, wid = tid >> 6, lane = tid & 63;
    const int wr = (wid >> 1) * 64, wc = (wid & 1) * 64;
    const int l16 = lane & 15, lhi = lane >> 4;
    const int lr8 = lane >> 3, lc8 = lane & 7;
    const int chunkp = lc8 ^ lr8;

    const ushort* aptr[4];
    const ushort* bptr[4];
#pragma unroll
    for (int q = 0; q < 4; ++q) {
        int r  = wid * 32 + q * 8 + lr8;
        int gr = rows[min(r, nrowsv - 1)];
        aptr[q] = xbf + (size_t)gr * DIM + chunkp * 8;
        int c = c0 + wid * 32 + q * 8 + lr8;
        bptr[q] = WeT + ((size_t)(e * DIM + c)) * DIM + chunkp * 8;
    }

    f32x4 acc[4][4];
#pragma unroll
    for (int m = 0; m < 4; ++m)
#pragma unroll
        for (int n = 0; n < 4; ++n) { f32x4 z = {0.f, 0.f, 0.f, 0.f}; acc[m][n] = z; }

#pragma unroll
    for (int q = 0; q < 4; ++q) {
        gload16(aptr[q], &Al[0][wid * 32 + q * 8][0]);
        gload16(bptr[q], &Bl[0][wid * 32 + q * 8][0]);
    }

    for (int s = 0; s < DIM / GBK; ++s) {
        const int buf = s & 1;
        if (s + 1 < DIM / GBK) {
            const int nb = buf ^ 1, k0 = (s + 1) * GBK;
#pragma unroll
            for (int q = 0; q < 4; ++q) {
                gload16(aptr[q] + k0, &Al[nb][wid * 32 + q * 8][0]);
                gload16(bptr[q] + k0, &Bl[nb][wid * 32 + q * 8][0]);
            }
            asm volatile("s_waitcnt vmcnt(8)" ::: "memory");
        } else {
            asm volatile("s_waitcnt vmcnt(0)" ::: "memory");
        }
        __builtin_amdgcn_s_barrier();

        const ushort* Ab = &Al[buf][0][0];
        const ushort* Bb = &Bl[buf][0][0];
#pragma unroll
        for (int h = 0; h < 2; ++h) {
            bf16x8 af[4], bfr[4];
            const int chb = (h * 4 + lhi) ^ (l16 & 7);
#pragma unroll
            for (int m = 0; m < 4; ++m) {
                int rr = wr + m * 16 + l16;
                af[m] = *(const bf16x8*)(Ab + rr * GBK + chb * 8);
            }
#pragma unroll
            for (int n = 0; n < 4; ++n) {
                int rr = wc + n * 16 + l16;
                bfr[n] = *(const bf16x8*)(Bb + rr * GBK + chb * 8);
            }
#pragma unroll
            for (int m = 0; m < 4; ++m)
#pragma unroll
                for (int n = 0; n < 4; ++n)
                    acc[m][n] = __builtin_amdgcn_mfma_f32_16x16x32_bf16(af[m], bfr[n], acc[m][n], 0, 0, 0);
        }
        asm volatile("s_waitcnt lgkmcnt(0)" ::: "memory");
        __builtin_amdgcn_s_barrier();
    }

    // epilogue: PASS 0 store, PASS 1 non-atomic read-add-store
    float bev[4];
#pragma unroll
    for (int n = 0; n < 4; ++n) bev[n] = be[(size_t)e * DIM + c0 + wc + n * 16 + l16];
#pragma unroll
    for (int m = 0; m < 4; ++m) {
#pragma unroll
        for (int r = 0; r < 4; ++r) {
            int rl = wr + m * 16 + lhi * 4 + r;
            if (rl < nrowsv) {
                int   gr = rows[rl];
                float w  = wrow[rl];
                float* op = out + (size_t)gr * DIM + c0 + wc;
#pragma unroll
                for (int n = 0; n < 4; ++n) {
                    float v   = w * (acc[m][n][r] + bev[n]);
                    int   col = n * 16 + l16;
                    if (PASS == 0) op[col] = v;
                    else           op[col] += v;
                }
            }
        }
    }
}

extern "C" void kernel_launch(void* const* d_in, const int* in_sizes, int n_in,
                              void* d_out, int out_size, void* d_ws, size_t ws_size,
                              hipStream_t stream) {
    const float* x     = (const float*)d_in[0];
    const float* noise = (const float*)d_in[1];
    const float* Wg    = (const float*)d_in[2];
    const float* Wn    = (const float*)d_in[3];
    const float* We    = (const float*)d_in[4];
    const float* be    = (const float*)d_in[5];
    float* out = (float*)d_out;

    char* w = (char*)d_ws;
    size_t off = 256;
    int*      cnt   = (int*)w;
    int*      idxl  = (int*)(w + off);      off += (size_t)2 * NE * NR * 4;   // 256 KB
    float*    wl    = (float*)(w + off);    off += (size_t)2 * NE * NR * 4;   // 256 KB
    uint32_t* eid   = (uint32_t*)(w + off); off += (size_t)NR * 4;            // 16 KB
    float2*   wpair = (float2*)(w + off);   off += (size_t)NR * 8;            // 32 KB
    off = (off + 255) & ~(size_t)255;
    ushort* xbf = (ushort*)(w + off); off += (size_t)NR * DIM * 2;            // 8 MB
    ushort* WeT = (ushort*)(w + off); off += (size_t)NE * DIM * DIM * 2;      // 16 MB

    k1_main<<<3072, 256, 0, stream>>>(We, WeT, x, noise, Wg, Wn, xbf, eid, wpair);
    bucket_build<<<16, 1024, 0, stream>>>(eid, wpair, cnt, idxl, wl);
    moe_gemm<0><<<40 * 8, 256, 0, stream>>>(xbf, WeT, be, cnt, idxl, wl, out);
    moe_gemm<1><<<40 * 8, 256, 0, stream>>>(xbf, WeT, be, cnt, idxl, wl, out);
}